// Round 6
// baseline (26180.402 us; speedup 1.0000x reference)
//
#include <hip/hip_runtime.h>
#include <stdint.h>

#define BB 64
#define TT 1024
#define EE 256
#define HH 512
#define NTAG 16

// ws layout in floats:
//   h_buf [2 bufs][2 dirs][64 b][512 j] = 131072
//   cnt[8 groups] at 131072, stride 64 ints (256B lines)
//   e_f [64][1024][16] at 131648 ; e_b after
#define HBUF_OFF 0
#define CNT_OFF  131072
#define EF_OFF   131648
#define EB_OFF   (EF_OFF + 1048576)

__device__ __forceinline__ float sigm(float v) { return 1.0f / (1.0f + __expf(-v)); }
__device__ __forceinline__ float tanh_f(float v) { return 1.0f - 2.0f / (__expf(2.0f * v) + 1.0f); }

template <int CTRL>
__device__ __forceinline__ float dpp_add(float v) {
  int d = __builtin_amdgcn_update_dpp(0, __float_as_int(v), CTRL, 0xF, 0xF, true);
  return v + __int_as_float(d);
}
// Sum across each 16-lane row (VALU-pipe DPP, no LDS traffic).
__device__ __forceinline__ float row16_reduce(float v) {
  v = dpp_add<0xB1>(v);    // quad_perm xor1
  v = dpp_add<0x4E>(v);    // quad_perm xor2
  v = dpp_add<0x124>(v);   // row_ror:4
  v = dpp_add<0x128>(v);   // row_ror:8
  return v;
}

__global__ void init_ws_kernel(float* ws) {
  int i = blockIdx.x * blockDim.x + threadIdx.x;
  if (i < EF_OFF) ws[i] = 0.0f;  // zeros h_buf + counters
}

// Persistent BiLSTM. 512 blocks x 256 threads, 80KiB LDS -> 2 independent
// blocks/CU (2 waves/SIMD from DIFFERENT blocks: one block's barrier/L3
// latency hides under the other's FMAs, with no shared __syncthreads).
// group = bid&7 (dir x 4 batch-quarters) -> XCD-aligned under bid%8 RR;
// jsl = bid>>3 (64 j-slices of 8 hidden units).
// Threads: 16 groups (bg 0..1, grg 0..7) x 16 K-chunks (kc).
// Thread tile: 8 batch x 4 gate-rows (one j-unit) over its K-chunk; DPP
// row-reduce across kc (lanes kc / kc+8 duplicate). W_hh slice [32][512]
// in LDS (64KB); h tile staged per j-half (16KB). Emission fused.
// Per-wait kill deadline (~3.5ms) -> any residency/drift failure terminates
// fast with wrong-but-bounded results instead of wedging the GPU.
__global__ void __launch_bounds__(256, 2)
lstm_kernel(const int* __restrict__ x, const float* __restrict__ emb,
            const float* __restrict__ w_ih_f, const float* __restrict__ w_hh_f,
            const float* __restrict__ b_f,
            const float* __restrict__ w_ih_b, const float* __restrict__ w_hh_b,
            const float* __restrict__ b_b,
            const float* __restrict__ w_fc, const float* __restrict__ b_fc,
            float* __restrict__ ws)
{
  extern __shared__ float smem[];
  float4* w4 = (float4*)smem;             // [32 gr][128 k4]  W_hh slice (64KB)
  float4* h4 = (float4*)(smem + 16384);   // [16 b][64 k4]    one j-half of h (16KB)

  const int tid = threadIdx.x;
  const int bid = blockIdx.x;
  const int group = bid & 7;
  const int jsl   = bid >> 3;            // 0..63
  const int dir   = group >> 2;
  const int bq    = group & 3;
  const int kc  = tid & 15;
  const int grp = tid >> 4;              // 0..15
  const int bg  = grp >> 3;              // 0..1
  const int grg = grp & 7;               // 0..7 (j-unit within slice)

  const float* w_ih = dir ? w_ih_b : w_ih_f;
  const float* w_hh = dir ? w_hh_b : w_hh_f;
  const float* bias = dir ? b_b : b_f;

  float* h_buf = ws + HBUF_OFF;
  int* cnt = (int*)(ws + CNT_OFF) + group * 64;
  float* earr = ws + (dir ? EB_OFF : EF_OFF);

  // ---- stage W_hh slice once: LDS row gr = jloc*4 + gate, j = jsl*8+jloc ----
  for (int it = 0; it < 16; ++it) {
    int idx = it * 256 + tid;            // f4 index over [32][128]
    int row = idx >> 7, k4 = idx & 127;
    int gate = row & 3, jloc = row >> 2;
    w4[idx] = *((const float4*)(w_hh + (size_t)(gate * 512 + jsl * 8 + jloc) * 512) + k4);
  }

  // per-lane output assignment: (b_l, j_l); lanes kc and kc+8 duplicate.
  const int bl   = kc & 7;
  const int j_l  = jsl * 8 + grg;
  const int b_l  = bq * 16 + bg * 8 + bl;
  const float bi_i = bias[0 * 512 + j_l], bi_f = bias[1 * 512 + j_l],
              bi_g = bias[2 * 512 + j_l], bi_o = bias[3 * 512 + j_l];

  // W_ih row pointers for this thread's 4 gate-rows
  const float4* wihp[4];
  #pragma unroll
  for (int r = 0; r < 4; ++r)
    wihp[r] = (const float4*)(w_ih + (size_t)(r * 512 + j_l) * 256);

  // emission assignment (grp<4): 4 dots/block over (16b x 16tag) per group
  const int dotid = jsl * 4 + grp;       // 0..255
  const int b_e = dotid >> 4;            // 0..15 (local row)
  const int tag = dotid & 15;
  const int gbe = bq * 16 + b_e;
  const float4* wfcp = (const float4*)(w_fc + (size_t)tag * 1024 + dir * 512);

  float c_reg = 0.0f, h_reg = 0.0f;
  bool dead = false;
  __syncthreads();                       // W staged

  for (int s = 0; s <= TT; ++s) {
    const bool last = (s == TT);
    const int t = dir ? (TT - 1 - s) : s;

    float acc[8][4];
    #pragma unroll
    for (int a = 0; a < 8; ++a)
      #pragma unroll
      for (int r = 0; r < 4; ++r) acc[a][r] = 0.0f;

    int xtok[8];
    // ---- x-part (no h dependency): before the barrier ----
    if (!last) {
      #pragma unroll
      for (int b2 = 0; b2 < 8; ++b2)
        xtok[b2] = x[(size_t)(bq * 16 + bg * 8 + b2) * TT + t];
      #pragma unroll
      for (int i = 0; i < 4; ++i) {
        float4 ev[8], wv[4];
        #pragma unroll
        for (int b2 = 0; b2 < 8; ++b2)
          ev[b2] = ((const float4*)(emb + (size_t)xtok[b2] * EE))[i * 16 + kc];
        #pragma unroll
        for (int r = 0; r < 4; ++r) wv[r] = wihp[r][i * 16 + kc];
        #pragma unroll
        for (int b2 = 0; b2 < 8; ++b2)
          #pragma unroll
          for (int r = 0; r < 4; ++r) {
            acc[b2][r] = fmaf(ev[b2].x, wv[r].x, acc[b2][r]);
            acc[b2][r] = fmaf(ev[b2].y, wv[r].y, acc[b2][r]);
            acc[b2][r] = fmaf(ev[b2].z, wv[r].z, acc[b2][r]);
            acc[b2][r] = fmaf(ev[b2].w, wv[r].w, acc[b2][r]);
          }
      }
    }

    // ---- group barrier: all 64 group blocks finished step s-1 ----
    if (tid == 0 && !dead) {
      const int target = 64 * s;
      long long deadline = clock64() + (1LL << 23);  // ~3.5ms budget PER WAIT
      int itc = 0;
      while (__hip_atomic_load(cnt, __ATOMIC_RELAXED, __HIP_MEMORY_SCOPE_AGENT) < target) {
        __builtin_amdgcn_s_sleep(2);
        if (((++itc) & 7) == 0 && clock64() > deadline) { dead = true; break; }
      }
      __threadfence();
    }
    __syncthreads();

    const float* hsrc = h_buf + ((size_t)((s & 1) * 2 + dir) * BB + bq * 16) * HH;
    float ep = 0.0f;

    #pragma unroll
    for (int hf = 0; hf < 2; ++hf) {
      if (hf == 1) __syncthreads();      // half0 consumers done before overwrite
      // stage one j-half of the 16-row h tile (coalesced, linear LDS)
      #pragma unroll
      for (int q = 0; q < 4; ++q) {
        int u = q * 256 + tid;
        int row = u >> 6, w = u & 63;
        h4[row * 64 + w] = ((const float4*)hsrc)[(size_t)row * 128 + hf * 64 + w];
      }
      __syncthreads();

      if (!last) {
        #pragma unroll
        for (int i = 0; i < 4; ++i) {
          float4 hv[8], wv[4];
          #pragma unroll
          for (int b2 = 0; b2 < 8; ++b2) hv[b2] = h4[(bg * 8 + b2) * 64 + i * 16 + kc];
          #pragma unroll
          for (int r = 0; r < 4; ++r) wv[r] = w4[(grg * 4 + r) * 128 + hf * 64 + i * 16 + kc];
          #pragma unroll
          for (int b2 = 0; b2 < 8; ++b2)
            #pragma unroll
            for (int r = 0; r < 4; ++r) {
              acc[b2][r] = fmaf(hv[b2].x, wv[r].x, acc[b2][r]);
              acc[b2][r] = fmaf(hv[b2].y, wv[r].y, acc[b2][r]);
              acc[b2][r] = fmaf(hv[b2].z, wv[r].z, acc[b2][r]);
              acc[b2][r] = fmaf(hv[b2].w, wv[r].w, acc[b2][r]);
            }
        }
      }
      // fused emission partial for the staged tile (= h[t_prev])
      if (s >= 1 && grp < 4) {
        #pragma unroll
        for (int i = 0; i < 4; ++i) {
          float4 hv = h4[b_e * 64 + i * 16 + kc];
          float4 wv = wfcp[hf * 64 + i * 16 + kc];
          ep += hv.x * wv.x + hv.y * wv.y + hv.z * wv.z + hv.w * wv.w;
        }
      }
    }

    if (!last) {
      // ---- reduce across kc (DPP, VALU pipe) ----
      #pragma unroll
      for (int a = 0; a < 8; ++a)
        #pragma unroll
        for (int r = 0; r < 4; ++r) acc[a][r] = row16_reduce(acc[a][r]);

      // ---- extract this lane's 4 gates + token (static indices per case) ----
      float g0, g1, g2, g3; int xvm;
      #define EXTRACT(K) case K: xvm = xtok[K]; \
        g0 = acc[K][0]; g1 = acc[K][1]; g2 = acc[K][2]; g3 = acc[K][3]; break;
      switch (bl) {
        EXTRACT(0) EXTRACT(1) EXTRACT(2) EXTRACT(3)
        EXTRACT(4) EXTRACT(5) EXTRACT(6)
        default: xvm = xtok[7];
          g0 = acc[7][0]; g1 = acc[7][1]; g2 = acc[7][2]; g3 = acc[7][3]; break;
      }
      #undef EXTRACT

      float igt = sigm(g0 + bi_i), fgt = sigm(g1 + bi_f);
      float ggt = tanh_f(g2 + bi_g), ogt = sigm(g3 + bi_o);
      float cn = fmaf(fgt, c_reg, igt * ggt);
      float hn = ogt * tanh_f(cn);
      bool mv = (xvm != 0);
      h_reg = mv ? hn : h_reg;
      c_reg = mv ? cn : c_reg;
      if (kc < 8)
        h_buf[((size_t)(((s + 1) & 1) * 2 + dir) * BB + b_l) * HH + j_l] = h_reg;
    }

    // ---- emission finalize ----
    if (s >= 1 && grp < 4) {
      float esum = row16_reduce(ep);
      if (kc == 0) {
        int t_prev = dir ? (TT - s) : (s - 1);
        int mm = (x[(size_t)gbe * TT + t_prev] != 0);
        float val = mm ? esum : 0.0f;
        if (dir == 0) val += b_fc[tag];
        earr[((size_t)gbe * TT + t_prev) * NTAG + tag] = val;
      }
    }

    __syncthreads();                     // h writes drained; LDS consumers done
    if (!last && tid == 0) { __threadfence(); atomicAdd(cnt, 1); }
  }
}

// Viterbi: one block (1 wave) per batch row. Lanes replicate j = lane&15.
__global__ void __launch_bounds__(64)
vit_kernel(const int* __restrict__ x, const float* __restrict__ trans,
           const float* __restrict__ ws, float* __restrict__ out)
{
  const int b = blockIdx.x;
  const int lane = threadIdx.x;
  const int j = lane & 15;
  const float* ef = ws + EF_OFF;
  const float* eb = ws + EB_OFF;

  __shared__ unsigned long long bp[TT];
  __shared__ int pathl[TT];

  float tcol[16];
  #pragma unroll
  for (int i = 0; i < 16; ++i) tcol[i] = trans[i * 16 + j];
  const float teos = trans[j * 16 + 2];

  float alpha = trans[1 * 16 + j]
              + ef[((size_t)b * TT + 0) * NTAG + j] + eb[((size_t)b * TT + 0) * NTAG + j];

  float ecur = ef[((size_t)b * TT + 1) * NTAG + j] + eb[((size_t)b * TT + 1) * NTAG + j];
  int mcur = (x[b * TT + 1] != 0);

  for (int t = 1; t < TT; ++t) {
    float enext = 0.0f; int mnext = 0;
    if (t + 1 < TT) {
      enext = ef[((size_t)b * TT + t + 1) * NTAG + j] + eb[((size_t)b * TT + t + 1) * NTAG + j];
      mnext = (x[b * TT + t + 1] != 0);
    }
    float best = -3.0e38f; int arg = 0;
    #pragma unroll
    for (int i = 0; i < 16; ++i) {
      float ai = __shfl(alpha, i);
      float sc = ai + tcol[i];
      if (sc > best) { best = sc; arg = i; }  // strict > => first max (jnp.argmax)
    }
    float an = best + ecur;
    int bpj = mcur ? arg : j;
    alpha = mcur ? an : alpha;
    unsigned long long nib = (unsigned long long)(bpj & 15) << (4 * j);
    #pragma unroll
    for (int d = 1; d < 16; d <<= 1) nib |= __shfl_xor(nib, d);
    if (lane == 0) bp[t] = nib;
    ecur = enext; mcur = mnext;
  }

  float endv = alpha + teos;
  int bi = j;
  #pragma unroll
  for (int d = 1; d < 64; d <<= 1) {
    float ov = __shfl_xor(endv, d);
    int oi = __shfl_xor(bi, d);
    if (ov > endv || (ov == endv && oi < bi)) { endv = ov; bi = oi; }
  }

  if (lane == 0) {
    out[b] = endv;
    int tag = bi;
    pathl[TT - 1] = tag;
    for (int t = TT - 1; t >= 1; --t) {
      tag = (int)((bp[t] >> (4 * tag)) & 15ull);
      pathl[t - 1] = tag;
    }
  }
  __syncthreads();
  for (int t = lane; t < TT; t += 64) {
    int mm = (x[b * TT + t] != 0);
    out[64 + (size_t)b * TT + t] = mm ? (float)pathl[t] : 0.0f;
  }
}

extern "C" void kernel_launch(void* const* d_in, const int* in_sizes, int n_in,
                              void* d_out, int out_size, void* d_ws, size_t ws_size,
                              hipStream_t stream) {
  (void)in_sizes; (void)n_in; (void)out_size; (void)ws_size;
  const int*   x    = (const int*)d_in[0];
  const float* emb  = (const float*)d_in[1];
  const float* wihf = (const float*)d_in[2];
  const float* whhf = (const float*)d_in[3];
  const float* bf   = (const float*)d_in[4];
  const float* wihb = (const float*)d_in[5];
  const float* whhb = (const float*)d_in[6];
  const float* bb   = (const float*)d_in[7];
  const float* wfc  = (const float*)d_in[8];
  const float* bfc  = (const float*)d_in[9];
  const float* tr   = (const float*)d_in[10];
  float* ws  = (float*)d_ws;
  float* out = (float*)d_out;

  (void)hipFuncSetAttribute((const void*)lstm_kernel,
                            hipFuncAttributeMaxDynamicSharedMemorySize, 81920);

  hipLaunchKernelGGL(init_ws_kernel, dim3(515), dim3(256), 0, stream, ws);
  hipLaunchKernelGGL(lstm_kernel, dim3(512), dim3(256), 81920, stream,
                     x, emb, wihf, whhf, bf, wihb, whhb, bb, wfc, bfc, ws);
  hipLaunchKernelGGL(vit_kernel, dim3(64), dim3(64), 0, stream, x, tr, ws, out);
}

// Round 7
// 15048.824 us; speedup vs baseline: 1.7397x; 1.7397x over previous
//
#include <hip/hip_runtime.h>
#include <stdint.h>

#define BB 64
#define TT 1024
#define EE 256
#define HH 512
#define NTAG 16

// ws layout in floats:
//   h_buf [2 bufs][2 dirs][64 b][512 j] = 131072
//   flags at 131072: 8 groups x 32 producers x 32-int stride (128B lines) = 8192 ints
//   e_f [64][1024][16] at 139264 ; e_b after
#define HBUF_OFF 0
#define FLAG_OFF 131072
#define EF_OFF   139264
#define EB_OFF   (EF_OFF + 1048576)

__device__ __forceinline__ float sigm(float v) { return 1.0f / (1.0f + __expf(-v)); }
__device__ __forceinline__ float tanh_f(float v) { return 1.0f - 2.0f / (__expf(2.0f * v) + 1.0f); }

template <int CTRL>
__device__ __forceinline__ float dpp_add(float v) {
  int d = __builtin_amdgcn_update_dpp(0, __float_as_int(v), CTRL, 0xF, 0xF, true);
  return v + __int_as_float(d);
}
// Sum across each 16-lane row (VALU-pipe DPP, no LDS traffic).
__device__ __forceinline__ float row16_reduce(float v) {
  v = dpp_add<0xB1>(v);    // quad_perm xor1
  v = dpp_add<0x4E>(v);    // quad_perm xor2
  v = dpp_add<0x124>(v);   // row_ror:4
  v = dpp_add<0x128>(v);   // row_ror:8
  return v;
}

__global__ void init_ws_kernel(float* ws) {
  int i = blockIdx.x * blockDim.x + threadIdx.x;
  if (i < EF_OFF) ws[i] = 0.0f;  // zeros h_buf + flags
}

// Persistent BiLSTM, XCD-local groups (proven 17.0ms config: 256 blocks x 256
// threads, 1/CU, acc[8][8]) with the central atomicAdd barrier replaced by
// per-producer release flags:
//   producer: one release-store flag[jsl]=s+1 per step (own 128B line, no RMW
//             contention, publishes in parallel across the 32 group blocks)
//   consumer: wave-0 lanes 0..31 poll the 32 flags in parallel (read-only
//             lines don't bounce), __all() combine, one acquire fence.
// 2-buffer safety: a block writes ring[(s+1)&1] only after seeing all flags
// >= s, i.e. every block finished reading ring[(s-1)&1] (same parity).
// Sticky per-wait deadline -> any stall ends fast with wrong-but-bounded
// output instead of wedging the GPU.
__global__ void __launch_bounds__(256, 1)
lstm_kernel(const int* __restrict__ x, const float* __restrict__ emb,
            const float* __restrict__ w_ih_f, const float* __restrict__ w_hh_f,
            const float* __restrict__ b_f,
            const float* __restrict__ w_ih_b, const float* __restrict__ w_hh_b,
            const float* __restrict__ b_b,
            const float* __restrict__ w_fc, const float* __restrict__ b_fc,
            float* __restrict__ ws)
{
  extern __shared__ float smem[];
  float4* w4 = (float4*)smem;             // [64 gr][128 k4]  W_hh slice (128KB)
  float4* h4 = (float4*)(smem + 32768);   // [16 b][64 k4]    one j-half of h (16KB)

  const int tid = threadIdx.x;
  const int bid = blockIdx.x;
  const int group = bid & 7;
  const int jsl   = bid >> 3;            // 0..31
  const int dir   = group >> 2;
  const int bq    = group & 3;
  const int kc  = tid & 15;
  const int grp = tid >> 4;              // 0..15
  const int bg  = grp >> 3;              // 0..1
  const int grg = grp & 7;               // 0..7

  const float* w_ih = dir ? w_ih_b : w_ih_f;
  const float* w_hh = dir ? w_hh_b : w_hh_f;
  const float* bias = dir ? b_b : b_f;

  float* h_buf = ws + HBUF_OFF;
  int* gflags = (int*)(ws + FLAG_OFF) + group * 1024;   // 32 flags x 32-int stride
  float* earr = ws + (dir ? EB_OFF : EF_OFF);

  // ---- stage W_hh slice once: LDS row gr = jloc*4 + gate, j = jsl*16+jloc ----
  for (int it = 0; it < 32; ++it) {
    int idx = it * 256 + tid;            // f4 index over [64][128]
    int row = idx >> 7, k4 = idx & 127;
    int gate = row & 3, jloc = row >> 2;
    w4[idx] = *((const float4*)(w_hh + (size_t)(gate * 512 + jsl * 16 + jloc) * 512) + k4);
  }

  // per-lane output assignment: (b_l, j_l)
  const int jj   = kc >> 3;              // 0..1
  const int bl   = kc & 7;               // 0..7
  const int j_l  = jsl * 16 + grg * 2 + jj;
  const int b_l  = bq * 16 + bg * 8 + bl;
  const float bi_i = bias[0 * 512 + j_l], bi_f = bias[1 * 512 + j_l],
              bi_g = bias[2 * 512 + j_l], bi_o = bias[3 * 512 + j_l];

  // W_ih row pointers for this thread's 8 gate-rows (r: jloc=grg*2+(r>>2), gate=r&3)
  const float4* wihp[8];
  #pragma unroll
  for (int r = 0; r < 8; ++r) {
    int gate = r & 3, jloc = grg * 2 + (r >> 2);
    wihp[r] = (const float4*)(w_ih + (size_t)(gate * 512 + jsl * 16 + jloc) * 256);
  }

  // emission assignment (grp<8): 8 dots/block over (16b x 16tag)
  const int dotid = jsl * 8 + grp;
  const int b_e = dotid >> 4;            // 0..15 (local row)
  const int tag = dotid & 15;
  const int gbe = bq * 16 + b_e;
  const float4* wfcp = (const float4*)(w_fc + (size_t)tag * 1024 + dir * 512);

  float c_reg = 0.0f, h_reg = 0.0f;
  bool dead = false;
  __syncthreads();                       // W staged

  for (int s = 0; s <= TT; ++s) {
    const bool last = (s == TT);
    const int t = dir ? (TT - 1 - s) : s;

    float acc[8][8];
    #pragma unroll
    for (int a = 0; a < 8; ++a)
      #pragma unroll
      for (int r = 0; r < 8; ++r) acc[a][r] = 0.0f;

    int xtok[8];
    // ---- x-part (no h dependency): before the flag-wait ----
    if (!last) {
      #pragma unroll
      for (int b2 = 0; b2 < 8; ++b2)
        xtok[b2] = x[(size_t)(bq * 16 + bg * 8 + b2) * TT + t];
      #pragma unroll
      for (int i = 0; i < 4; ++i) {
        float4 ev[8], wv[8];
        #pragma unroll
        for (int b2 = 0; b2 < 8; ++b2)
          ev[b2] = ((const float4*)(emb + (size_t)xtok[b2] * EE))[i * 16 + kc];
        #pragma unroll
        for (int r = 0; r < 8; ++r) wv[r] = wihp[r][i * 16 + kc];
        #pragma unroll
        for (int b2 = 0; b2 < 8; ++b2)
          #pragma unroll
          for (int r = 0; r < 8; ++r) {
            acc[b2][r] = fmaf(ev[b2].x, wv[r].x, acc[b2][r]);
            acc[b2][r] = fmaf(ev[b2].y, wv[r].y, acc[b2][r]);
            acc[b2][r] = fmaf(ev[b2].z, wv[r].z, acc[b2][r]);
            acc[b2][r] = fmaf(ev[b2].w, wv[r].w, acc[b2][r]);
          }
      }
    }

    // ---- flag-wait: all 32 group producers published step s ----
    if (tid < 64 && !dead) {
      bool ok = (tid >= 32);
      if (!ok)
        ok = (__hip_atomic_load(gflags + tid * 32, __ATOMIC_RELAXED,
                                __HIP_MEMORY_SCOPE_AGENT) >= s);
      long long deadline = clock64() + (1LL << 23);  // ~3.5ms budget PER WAIT
      int itc = 0;
      while (!__all(ok)) {
        __builtin_amdgcn_s_sleep(1);
        if (!ok)
          ok = (__hip_atomic_load(gflags + tid * 32, __ATOMIC_RELAXED,
                                  __HIP_MEMORY_SCOPE_AGENT) >= s);
        if (((++itc) & 15) == 0 && clock64() > deadline) { dead = true; break; }
      }
      __threadfence();  // acquire: order h_buf reads after observed flags
    }
    __syncthreads();

    const float* hsrc = h_buf + ((size_t)((s & 1) * 2 + dir) * BB + bq * 16) * HH;
    float ep = 0.0f;

    #pragma unroll
    for (int hf = 0; hf < 2; ++hf) {
      if (hf == 1) __syncthreads();      // half0 consumers done before overwrite
      // stage one j-half of the 16-row h tile (coalesced, linear LDS)
      #pragma unroll
      for (int q = 0; q < 4; ++q) {
        int u = q * 256 + tid;
        int row = u >> 6, w = u & 63;
        h4[row * 64 + w] = ((const float4*)hsrc)[(size_t)row * 128 + hf * 64 + w];
      }
      __syncthreads();

      if (!last) {
        #pragma unroll
        for (int i = 0; i < 4; ++i) {
          float4 hv[8], wv[8];
          #pragma unroll
          for (int b2 = 0; b2 < 8; ++b2) hv[b2] = h4[(bg * 8 + b2) * 64 + i * 16 + kc];
          #pragma unroll
          for (int r = 0; r < 8; ++r) wv[r] = w4[(grg * 8 + r) * 128 + hf * 64 + i * 16 + kc];
          #pragma unroll
          for (int b2 = 0; b2 < 8; ++b2)
            #pragma unroll
            for (int r = 0; r < 8; ++r) {
              acc[b2][r] = fmaf(hv[b2].x, wv[r].x, acc[b2][r]);
              acc[b2][r] = fmaf(hv[b2].y, wv[r].y, acc[b2][r]);
              acc[b2][r] = fmaf(hv[b2].z, wv[r].z, acc[b2][r]);
              acc[b2][r] = fmaf(hv[b2].w, wv[r].w, acc[b2][r]);
            }
        }
      }
      // fused emission partial for the staged tile (= h[t_prev])
      if (s >= 1 && grp < 8) {
        #pragma unroll
        for (int i = 0; i < 4; ++i) {
          float4 hv = h4[b_e * 64 + i * 16 + kc];
          float4 wv = wfcp[hf * 64 + i * 16 + kc];
          ep += hv.x * wv.x + hv.y * wv.y + hv.z * wv.z + hv.w * wv.w;
        }
      }
    }

    if (!last) {
      // ---- reduce across kc (DPP, VALU pipe) ----
      #pragma unroll
      for (int a = 0; a < 8; ++a)
        #pragma unroll
        for (int r = 0; r < 8; ++r) acc[a][r] = row16_reduce(acc[a][r]);

      // ---- extract this lane's 4 gates + token (static indices per case) ----
      float g0, g1, g2, g3; int xvm;
      #define EXTRACT(K) case K: xvm = xtok[(K) & 7]; \
        g0 = acc[(K) & 7][((K) >> 3) * 4 + 0]; g1 = acc[(K) & 7][((K) >> 3) * 4 + 1]; \
        g2 = acc[(K) & 7][((K) >> 3) * 4 + 2]; g3 = acc[(K) & 7][((K) >> 3) * 4 + 3]; break;
      switch (kc) {
        EXTRACT(0) EXTRACT(1) EXTRACT(2) EXTRACT(3)
        EXTRACT(4) EXTRACT(5) EXTRACT(6) EXTRACT(7)
        EXTRACT(8) EXTRACT(9) EXTRACT(10) EXTRACT(11)
        EXTRACT(12) EXTRACT(13) EXTRACT(14)
        default: xvm = xtok[7];
          g0 = acc[7][4]; g1 = acc[7][5]; g2 = acc[7][6]; g3 = acc[7][7]; break;
      }
      #undef EXTRACT

      float igt = sigm(g0 + bi_i), fgt = sigm(g1 + bi_f);
      float ggt = tanh_f(g2 + bi_g), ogt = sigm(g3 + bi_o);
      float cn = fmaf(fgt, c_reg, igt * ggt);
      float hn = ogt * tanh_f(cn);
      bool mv = (xvm != 0);
      h_reg = mv ? hn : h_reg;
      c_reg = mv ? cn : c_reg;
      h_buf[((size_t)(((s + 1) & 1) * 2 + dir) * BB + b_l) * HH + j_l] = h_reg;
    }

    // ---- emission finalize ----
    if (s >= 1 && grp < 8) {
      float esum = row16_reduce(ep);
      if (kc == 0) {
        int t_prev = dir ? (TT - s) : (s - 1);
        int mm = (x[(size_t)gbe * TT + t_prev] != 0);
        float val = mm ? esum : 0.0f;
        if (dir == 0) val += b_fc[tag];
        earr[((size_t)gbe * TT + t_prev) * NTAG + tag] = val;
      }
    }

    __syncthreads();                     // h writes drained; LDS consumers done
    if (!last && tid == 0)
      __hip_atomic_store(gflags + jsl * 32, s + 1, __ATOMIC_RELEASE,
                         __HIP_MEMORY_SCOPE_AGENT);   // parallel publish, no RMW
  }
}

// Viterbi: one block (1 wave) per batch row. Lanes replicate j = lane&15.
__global__ void __launch_bounds__(64)
vit_kernel(const int* __restrict__ x, const float* __restrict__ trans,
           const float* __restrict__ ws, float* __restrict__ out)
{
  const int b = blockIdx.x;
  const int lane = threadIdx.x;
  const int j = lane & 15;
  const float* ef = ws + EF_OFF;
  const float* eb = ws + EB_OFF;

  __shared__ unsigned long long bp[TT];
  __shared__ int pathl[TT];

  float tcol[16];
  #pragma unroll
  for (int i = 0; i < 16; ++i) tcol[i] = trans[i * 16 + j];
  const float teos = trans[j * 16 + 2];

  float alpha = trans[1 * 16 + j]
              + ef[((size_t)b * TT + 0) * NTAG + j] + eb[((size_t)b * TT + 0) * NTAG + j];

  float ecur = ef[((size_t)b * TT + 1) * NTAG + j] + eb[((size_t)b * TT + 1) * NTAG + j];
  int mcur = (x[b * TT + 1] != 0);

  for (int t = 1; t < TT; ++t) {
    float enext = 0.0f; int mnext = 0;
    if (t + 1 < TT) {
      enext = ef[((size_t)b * TT + t + 1) * NTAG + j] + eb[((size_t)b * TT + t + 1) * NTAG + j];
      mnext = (x[b * TT + t + 1] != 0);
    }
    float best = -3.0e38f; int arg = 0;
    #pragma unroll
    for (int i = 0; i < 16; ++i) {
      float ai = __shfl(alpha, i);
      float sc = ai + tcol[i];
      if (sc > best) { best = sc; arg = i; }  // strict > => first max (jnp.argmax)
    }
    float an = best + ecur;
    int bpj = mcur ? arg : j;
    alpha = mcur ? an : alpha;
    unsigned long long nib = (unsigned long long)(bpj & 15) << (4 * j);
    #pragma unroll
    for (int d = 1; d < 16; d <<= 1) nib |= __shfl_xor(nib, d);
    if (lane == 0) bp[t] = nib;
    ecur = enext; mcur = mnext;
  }

  float endv = alpha + teos;
  int bi = j;
  #pragma unroll
  for (int d = 1; d < 64; d <<= 1) {
    float ov = __shfl_xor(endv, d);
    int oi = __shfl_xor(bi, d);
    if (ov > endv || (ov == endv && oi < bi)) { endv = ov; bi = oi; }
  }

  if (lane == 0) {
    out[b] = endv;
    int tag = bi;
    pathl[TT - 1] = tag;
    for (int t = TT - 1; t >= 1; --t) {
      tag = (int)((bp[t] >> (4 * tag)) & 15ull);
      pathl[t - 1] = tag;
    }
  }
  __syncthreads();
  for (int t = lane; t < TT; t += 64) {
    int mm = (x[b * TT + t] != 0);
    out[64 + (size_t)b * TT + t] = mm ? (float)pathl[t] : 0.0f;
  }
}

extern "C" void kernel_launch(void* const* d_in, const int* in_sizes, int n_in,
                              void* d_out, int out_size, void* d_ws, size_t ws_size,
                              hipStream_t stream) {
  (void)in_sizes; (void)n_in; (void)out_size; (void)ws_size;
  const int*   x    = (const int*)d_in[0];
  const float* emb  = (const float*)d_in[1];
  const float* wihf = (const float*)d_in[2];
  const float* whhf = (const float*)d_in[3];
  const float* bf   = (const float*)d_in[4];
  const float* wihb = (const float*)d_in[5];
  const float* whhb = (const float*)d_in[6];
  const float* bb   = (const float*)d_in[7];
  const float* wfc  = (const float*)d_in[8];
  const float* bfc  = (const float*)d_in[9];
  const float* tr   = (const float*)d_in[10];
  float* ws  = (float*)d_ws;
  float* out = (float*)d_out;

  (void)hipFuncSetAttribute((const void*)lstm_kernel,
                            hipFuncAttributeMaxDynamicSharedMemorySize, 147456);

  hipLaunchKernelGGL(init_ws_kernel, dim3(544), dim3(256), 0, stream, ws);
  hipLaunchKernelGGL(lstm_kernel, dim3(256), dim3(256), 147456, stream,
                     x, emb, wihf, whhf, bf, wihb, whhb, bb, wfc, bfc, ws);
  hipLaunchKernelGGL(vit_kernel, dim3(64), dim3(64), 0, stream, x, tr, ws, out);
}

// Round 8
// 12553.328 us; speedup vs baseline: 2.0855x; 1.1988x over previous
//
#include <hip/hip_runtime.h>
#include <stdint.h>

#define BB 64
#define TT 1024
#define EE 256
#define HH 512
#define NTAG 16

// ws layout in floats:
//   h_buf [2 bufs][2 dirs][64 b][512 j] = 131072
//   flags at 131072: 8 groups x 32 producers x 32-int stride (128B lines) = 8192 ints
//   e_f [64][1024][16] at 139264 ; e_b after
#define HBUF_OFF 0
#define FLAG_OFF 131072
#define EF_OFF   139264
#define EB_OFF   (EF_OFF + 1048576)

__device__ __forceinline__ float sigm(float v) { return 1.0f / (1.0f + __expf(-v)); }
__device__ __forceinline__ float tanh_f(float v) { return 1.0f - 2.0f / (__expf(2.0f * v) + 1.0f); }

template <int CTRL>
__device__ __forceinline__ float dpp_add(float v) {
  int d = __builtin_amdgcn_update_dpp(0, __float_as_int(v), CTRL, 0xF, 0xF, true);
  return v + __int_as_float(d);
}
// Sum across each 16-lane row (VALU-pipe DPP, no LDS traffic).
__device__ __forceinline__ float row16_reduce(float v) {
  v = dpp_add<0xB1>(v);    // quad_perm xor1
  v = dpp_add<0x4E>(v);    // quad_perm xor2
  v = dpp_add<0x124>(v);   // row_ror:4
  v = dpp_add<0x128>(v);   // row_ror:8
  return v;
}

__global__ void init_ws_kernel(float* ws) {
  int i = blockIdx.x * blockDim.x + threadIdx.x;
  if (i < EF_OFF) ws[i] = 0.0f;  // zeros h_buf + flags
}

// Persistent BiLSTM (R7 15.0ms config: 256 blocks x 256 threads, 1/CU,
// acc[8][8], per-producer flags) with FENCE-FREE h exchange:
//   producer: h written via agent-scope RELAXED ATOMIC stores (sc1 ->
//             write-through to the L3 coherence point; nothing dirty in L2).
//             __syncthreads' implicit vmcnt(0) drains them, then a relaxed
//             flag publish (own 128B line, no RMW).
//   consumer: polls 32 flags in parallel (agent atomic loads), then stages h
//             via agent-scope RELAXED ATOMIC loads (sc1, bypass local L2).
//             NO __threadfence -> L2 is never invalidated -> W_ih/emb/x stay
//             L2-hot across all 1024 steps (prev: re-fetched from L3 every
//             step after the acquire fence's invalidate).
// 2-buffer safety: a block writes ring[(s+1)&1] only after seeing all flags
// >= s, i.e. every block finished reading ring[(s-1)&1] (same parity).
// Sticky per-wait deadline -> any stall ends fast with wrong-but-bounded
// output instead of wedging the GPU.
__global__ void __launch_bounds__(256, 1)
lstm_kernel(const int* __restrict__ x, const float* __restrict__ emb,
            const float* __restrict__ w_ih_f, const float* __restrict__ w_hh_f,
            const float* __restrict__ b_f,
            const float* __restrict__ w_ih_b, const float* __restrict__ w_hh_b,
            const float* __restrict__ b_b,
            const float* __restrict__ w_fc, const float* __restrict__ b_fc,
            float* __restrict__ ws)
{
  extern __shared__ float smem[];
  float4* w4 = (float4*)smem;             // [64 gr][128 k4]  W_hh slice (128KB)
  float4* h4 = (float4*)(smem + 32768);   // [16 b][64 k4]    one j-half of h (16KB)

  const int tid = threadIdx.x;
  const int bid = blockIdx.x;
  const int group = bid & 7;
  const int jsl   = bid >> 3;            // 0..31
  const int dir   = group >> 2;
  const int bq    = group & 3;
  const int kc  = tid & 15;
  const int grp = tid >> 4;              // 0..15
  const int bg  = grp >> 3;              // 0..1
  const int grg = grp & 7;               // 0..7

  const float* w_ih = dir ? w_ih_b : w_ih_f;
  const float* w_hh = dir ? w_hh_b : w_hh_f;
  const float* bias = dir ? b_b : b_f;

  float* h_buf = ws + HBUF_OFF;
  int* gflags = (int*)(ws + FLAG_OFF) + group * 1024;   // 32 flags x 32-int stride
  float* earr = ws + (dir ? EB_OFF : EF_OFF);

  // ---- stage W_hh slice once: LDS row gr = jloc*4 + gate, j = jsl*16+jloc ----
  for (int it = 0; it < 32; ++it) {
    int idx = it * 256 + tid;            // f4 index over [64][128]
    int row = idx >> 7, k4 = idx & 127;
    int gate = row & 3, jloc = row >> 2;
    w4[idx] = *((const float4*)(w_hh + (size_t)(gate * 512 + jsl * 16 + jloc) * 512) + k4);
  }

  // per-lane output assignment: (b_l, j_l)
  const int jj   = kc >> 3;              // 0..1
  const int bl   = kc & 7;               // 0..7
  const int j_l  = jsl * 16 + grg * 2 + jj;
  const int b_l  = bq * 16 + bg * 8 + bl;
  const float bi_i = bias[0 * 512 + j_l], bi_f = bias[1 * 512 + j_l],
              bi_g = bias[2 * 512 + j_l], bi_o = bias[3 * 512 + j_l];

  // W_ih row pointers for this thread's 8 gate-rows (r: jloc=grg*2+(r>>2), gate=r&3)
  const float4* wihp[8];
  #pragma unroll
  for (int r = 0; r < 8; ++r) {
    int gate = r & 3, jloc = grg * 2 + (r >> 2);
    wihp[r] = (const float4*)(w_ih + (size_t)(gate * 512 + jsl * 16 + jloc) * 256);
  }

  // emission assignment (grp<8): 8 dots/block over (16b x 16tag)
  const int dotid = jsl * 8 + grp;
  const int b_e = dotid >> 4;            // 0..15 (local row)
  const int tag = dotid & 15;
  const int gbe = bq * 16 + b_e;
  const float4* wfcp = (const float4*)(w_fc + (size_t)tag * 1024 + dir * 512);

  float c_reg = 0.0f, h_reg = 0.0f;
  bool dead = false;
  __syncthreads();                       // W staged

  for (int s = 0; s <= TT; ++s) {
    const bool last = (s == TT);
    const int t = dir ? (TT - 1 - s) : s;

    float acc[8][8];
    #pragma unroll
    for (int a = 0; a < 8; ++a)
      #pragma unroll
      for (int r = 0; r < 8; ++r) acc[a][r] = 0.0f;

    int xtok[8];
    // ---- x-part (no h dependency): before the flag-wait; L2-hot ----
    if (!last) {
      #pragma unroll
      for (int b2 = 0; b2 < 8; ++b2)
        xtok[b2] = x[(size_t)(bq * 16 + bg * 8 + b2) * TT + t];
      #pragma unroll
      for (int i = 0; i < 4; ++i) {
        float4 ev[8], wv[8];
        #pragma unroll
        for (int b2 = 0; b2 < 8; ++b2)
          ev[b2] = ((const float4*)(emb + (size_t)xtok[b2] * EE))[i * 16 + kc];
        #pragma unroll
        for (int r = 0; r < 8; ++r) wv[r] = wihp[r][i * 16 + kc];
        #pragma unroll
        for (int b2 = 0; b2 < 8; ++b2)
          #pragma unroll
          for (int r = 0; r < 8; ++r) {
            acc[b2][r] = fmaf(ev[b2].x, wv[r].x, acc[b2][r]);
            acc[b2][r] = fmaf(ev[b2].y, wv[r].y, acc[b2][r]);
            acc[b2][r] = fmaf(ev[b2].z, wv[r].z, acc[b2][r]);
            acc[b2][r] = fmaf(ev[b2].w, wv[r].w, acc[b2][r]);
          }
      }
    }

    // ---- flag-wait: all 32 group producers published step s (no fence) ----
    if (tid < 64 && !dead) {
      bool ok = (tid >= 32);
      if (!ok)
        ok = (__hip_atomic_load(gflags + tid * 32, __ATOMIC_RELAXED,
                                __HIP_MEMORY_SCOPE_AGENT) >= s);
      long long deadline = clock64() + (1LL << 23);  // ~3.5ms budget PER WAIT
      int itc = 0;
      while (!__all(ok)) {
        __builtin_amdgcn_s_sleep(1);
        if (!ok)
          ok = (__hip_atomic_load(gflags + tid * 32, __ATOMIC_RELAXED,
                                  __HIP_MEMORY_SCOPE_AGENT) >= s);
        if (((++itc) & 15) == 0 && clock64() > deadline) { dead = true; break; }
      }
    }
    __syncthreads();

    const float* hsrc = h_buf + ((size_t)((s & 1) * 2 + dir) * BB + bq * 16) * HH;
    float ep = 0.0f;

    #pragma unroll
    for (int hf = 0; hf < 2; ++hf) {
      if (hf == 1) __syncthreads();      // half0 consumers done before overwrite
      // stage one j-half of the 16-row h tile via sc1 atomic loads (L3-fresh,
      // local L2 untouched)
      #pragma unroll
      for (int q = 0; q < 4; ++q) {
        int u = q * 256 + tid;
        int row = u >> 6, w = u & 63;
        const float* src = hsrc + (size_t)row * 512 + hf * 256 + w * 4;
        float4 v;
        v.x = __hip_atomic_load(src + 0, __ATOMIC_RELAXED, __HIP_MEMORY_SCOPE_AGENT);
        v.y = __hip_atomic_load(src + 1, __ATOMIC_RELAXED, __HIP_MEMORY_SCOPE_AGENT);
        v.z = __hip_atomic_load(src + 2, __ATOMIC_RELAXED, __HIP_MEMORY_SCOPE_AGENT);
        v.w = __hip_atomic_load(src + 3, __ATOMIC_RELAXED, __HIP_MEMORY_SCOPE_AGENT);
        h4[row * 64 + w] = v;
      }
      __syncthreads();

      if (!last) {
        #pragma unroll
        for (int i = 0; i < 4; ++i) {
          float4 hv[8], wv[8];
          #pragma unroll
          for (int b2 = 0; b2 < 8; ++b2) hv[b2] = h4[(bg * 8 + b2) * 64 + i * 16 + kc];
          #pragma unroll
          for (int r = 0; r < 8; ++r) wv[r] = w4[(grg * 8 + r) * 128 + hf * 64 + i * 16 + kc];
          #pragma unroll
          for (int b2 = 0; b2 < 8; ++b2)
            #pragma unroll
            for (int r = 0; r < 8; ++r) {
              acc[b2][r] = fmaf(hv[b2].x, wv[r].x, acc[b2][r]);
              acc[b2][r] = fmaf(hv[b2].y, wv[r].y, acc[b2][r]);
              acc[b2][r] = fmaf(hv[b2].z, wv[r].z, acc[b2][r]);
              acc[b2][r] = fmaf(hv[b2].w, wv[r].w, acc[b2][r]);
            }
        }
      }
      // fused emission partial for the staged tile (= h[t_prev])
      if (s >= 1 && grp < 8) {
        #pragma unroll
        for (int i = 0; i < 4; ++i) {
          float4 hv = h4[b_e * 64 + i * 16 + kc];
          float4 wv = wfcp[hf * 64 + i * 16 + kc];
          ep += hv.x * wv.x + hv.y * wv.y + hv.z * wv.z + hv.w * wv.w;
        }
      }
    }

    if (!last) {
      // ---- reduce across kc (DPP, VALU pipe) ----
      #pragma unroll
      for (int a = 0; a < 8; ++a)
        #pragma unroll
        for (int r = 0; r < 8; ++r) acc[a][r] = row16_reduce(acc[a][r]);

      // ---- extract this lane's 4 gates + token (static indices per case) ----
      float g0, g1, g2, g3; int xvm;
      #define EXTRACT(K) case K: xvm = xtok[(K) & 7]; \
        g0 = acc[(K) & 7][((K) >> 3) * 4 + 0]; g1 = acc[(K) & 7][((K) >> 3) * 4 + 1]; \
        g2 = acc[(K) & 7][((K) >> 3) * 4 + 2]; g3 = acc[(K) & 7][((K) >> 3) * 4 + 3]; break;
      switch (kc) {
        EXTRACT(0) EXTRACT(1) EXTRACT(2) EXTRACT(3)
        EXTRACT(4) EXTRACT(5) EXTRACT(6) EXTRACT(7)
        EXTRACT(8) EXTRACT(9) EXTRACT(10) EXTRACT(11)
        EXTRACT(12) EXTRACT(13) EXTRACT(14)
        default: xvm = xtok[7];
          g0 = acc[7][4]; g1 = acc[7][5]; g2 = acc[7][6]; g3 = acc[7][7]; break;
      }
      #undef EXTRACT

      float igt = sigm(g0 + bi_i), fgt = sigm(g1 + bi_f);
      float ggt = tanh_f(g2 + bi_g), ogt = sigm(g3 + bi_o);
      float cn = fmaf(fgt, c_reg, igt * ggt);
      float hn = ogt * tanh_f(cn);
      bool mv = (xvm != 0);
      h_reg = mv ? hn : h_reg;
      c_reg = mv ? cn : c_reg;
      // sc1 write-through store: visible at the coherence point once vmcnt
      // drains (the __syncthreads below waits vmcnt(0) for every thread).
      __hip_atomic_store(
          &h_buf[((size_t)(((s + 1) & 1) * 2 + dir) * BB + b_l) * HH + j_l],
          h_reg, __ATOMIC_RELAXED, __HIP_MEMORY_SCOPE_AGENT);
    }

    // ---- emission finalize ----
    if (s >= 1 && grp < 8) {
      float esum = row16_reduce(ep);
      if (kc == 0) {
        int t_prev = dir ? (TT - s) : (s - 1);
        int mm = (x[(size_t)gbe * TT + t_prev] != 0);
        float val = mm ? esum : 0.0f;
        if (dir == 0) val += b_fc[tag];
        earr[((size_t)gbe * TT + t_prev) * NTAG + tag] = val;
      }
    }

    __syncthreads();                     // all h sc1-stores drained (vmcnt 0)
    if (!last && tid == 0)
      __hip_atomic_store(gflags + jsl * 32, s + 1, __ATOMIC_RELAXED,
                         __HIP_MEMORY_SCOPE_AGENT);   // parallel publish, no RMW
  }
}

// Viterbi: one block (1 wave) per batch row. Lanes replicate j = lane&15.
__global__ void __launch_bounds__(64)
vit_kernel(const int* __restrict__ x, const float* __restrict__ trans,
           const float* __restrict__ ws, float* __restrict__ out)
{
  const int b = blockIdx.x;
  const int lane = threadIdx.x;
  const int j = lane & 15;
  const float* ef = ws + EF_OFF;
  const float* eb = ws + EB_OFF;

  __shared__ unsigned long long bp[TT];
  __shared__ int pathl[TT];

  float tcol[16];
  #pragma unroll
  for (int i = 0; i < 16; ++i) tcol[i] = trans[i * 16 + j];
  const float teos = trans[j * 16 + 2];

  float alpha = trans[1 * 16 + j]
              + ef[((size_t)b * TT + 0) * NTAG + j] + eb[((size_t)b * TT + 0) * NTAG + j];

  float ecur = ef[((size_t)b * TT + 1) * NTAG + j] + eb[((size_t)b * TT + 1) * NTAG + j];
  int mcur = (x[b * TT + 1] != 0);

  for (int t = 1; t < TT; ++t) {
    float enext = 0.0f; int mnext = 0;
    if (t + 1 < TT) {
      enext = ef[((size_t)b * TT + t + 1) * NTAG + j] + eb[((size_t)b * TT + t + 1) * NTAG + j];
      mnext = (x[b * TT + t + 1] != 0);
    }
    float best = -3.0e38f; int arg = 0;
    #pragma unroll
    for (int i = 0; i < 16; ++i) {
      float ai = __shfl(alpha, i);
      float sc = ai + tcol[i];
      if (sc > best) { best = sc; arg = i; }  // strict > => first max (jnp.argmax)
    }
    float an = best + ecur;
    int bpj = mcur ? arg : j;
    alpha = mcur ? an : alpha;
    unsigned long long nib = (unsigned long long)(bpj & 15) << (4 * j);
    #pragma unroll
    for (int d = 1; d < 16; d <<= 1) nib |= __shfl_xor(nib, d);
    if (lane == 0) bp[t] = nib;
    ecur = enext; mcur = mnext;
  }

  float endv = alpha + teos;
  int bi = j;
  #pragma unroll
  for (int d = 1; d < 64; d <<= 1) {
    float ov = __shfl_xor(endv, d);
    int oi = __shfl_xor(bi, d);
    if (ov > endv || (ov == endv && oi < bi)) { endv = ov; bi = oi; }
  }

  if (lane == 0) {
    out[b] = endv;
    int tag = bi;
    pathl[TT - 1] = tag;
    for (int t = TT - 1; t >= 1; --t) {
      tag = (int)((bp[t] >> (4 * tag)) & 15ull);
      pathl[t - 1] = tag;
    }
  }
  __syncthreads();
  for (int t = lane; t < TT; t += 64) {
    int mm = (x[b * TT + t] != 0);
    out[64 + (size_t)b * TT + t] = mm ? (float)pathl[t] : 0.0f;
  }
}

extern "C" void kernel_launch(void* const* d_in, const int* in_sizes, int n_in,
                              void* d_out, int out_size, void* d_ws, size_t ws_size,
                              hipStream_t stream) {
  (void)in_sizes; (void)n_in; (void)out_size; (void)ws_size;
  const int*   x    = (const int*)d_in[0];
  const float* emb  = (const float*)d_in[1];
  const float* wihf = (const float*)d_in[2];
  const float* whhf = (const float*)d_in[3];
  const float* bf   = (const float*)d_in[4];
  const float* wihb = (const float*)d_in[5];
  const float* whhb = (const float*)d_in[6];
  const float* bb   = (const float*)d_in[7];
  const float* wfc  = (const float*)d_in[8];
  const float* bfc  = (const float*)d_in[9];
  const float* tr   = (const float*)d_in[10];
  float* ws  = (float*)d_ws;
  float* out = (float*)d_out;

  (void)hipFuncSetAttribute((const void*)lstm_kernel,
                            hipFuncAttributeMaxDynamicSharedMemorySize, 147456);

  hipLaunchKernelGGL(init_ws_kernel, dim3(544), dim3(256), 0, stream, ws);
  hipLaunchKernelGGL(lstm_kernel, dim3(256), dim3(256), 147456, stream,
                     x, emb, wihf, whhf, bf, wihb, whhb, bb, wfc, bfc, ws);
  hipLaunchKernelGGL(vit_kernel, dim3(64), dim3(64), 0, stream, x, tr, ws, out);
}